// Round 2
// baseline (2033.840 us; speedup 1.0000x reference)
//
#include <hip/hip_runtime.h>
#include <stdint.h>
#include <math.h>

// Problem constants (fixed by the reference)
#define T_TOK 8192      // B*S tokens
#define H_DIM 2048
#define I_DIM 1024
#define E_NUM 16
#define K_TOP 8
#define R_RANK 602
#define RP 640          // rank padded to 5*128 (zero-padded weights)
#define NPAIR 65536     // T_TOK * K_TOP (exact)
#define NPAIR_PAD (NPAIR + 256)
#define MAX_TILES 272   // sum ceil(Ne/256) <= 65536/256 + 16

typedef __attribute__((ext_vector_type(8))) short short8;
typedef __attribute__((ext_vector_type(4))) short short4v;
typedef __attribute__((ext_vector_type(4))) float f32x4;

__device__ __forceinline__ float bf2f(unsigned short s) {
  union { unsigned int i; float f; } u; u.i = ((unsigned int)s) << 16; return u.f;
}
__device__ __forceinline__ unsigned short f2bf(float f) {
  union { float f; unsigned int i; } u; u.f = f;
  unsigned int r = u.i + 0x7FFFu + ((u.i >> 16) & 1u);   // RNE, inputs finite
  return (unsigned short)(r >> 16);
}

typedef __attribute__((address_space(1))) const unsigned int glob_u32;
typedef __attribute__((address_space(3))) unsigned int lds_u32;

__device__ __forceinline__ void gload16(const void* g, void* l) {
  // async global->LDS, 16B per lane; LDS dest must be wave-uniform base + lane*16
  __builtin_amdgcn_global_load_lds((glob_u32*)g, (lds_u32*)l, 16, 0, 0);
}

// int-metadata buffer layout (in units of int)
#define IB_CNT  0
#define IB_OFFS 16
#define IB_CURS 33
#define IB_NT   49
#define IB_TE   50
#define IB_TP   (50 + MAX_TILES)
#define IB_TOTAL (50 + 2 * MAX_TILES)

// XCD-chunked bijective swizzle: consecutive work-ids on the SAME XCD,
// N-fastest decode so all n-tiles of one A-tile run back-to-back on one L2.
// Valid bijection when W % 8 == 0 (all our grids are multiples of 8).
__device__ __forceinline__ void swz_decode(int L, int W, int ny, int& bx, int& n0) {
  int w = (L & 7) * (W >> 3) + (L >> 3);
  bx = w / ny;
  n0 = (w - bx * ny) * 128;
}

// ---------------- logits + top-8 (no atomics; 4 waves/block, wave per token) ----------------
__global__ __launch_bounds__(256) void k_logits(
    const float* __restrict__ x, const float* __restrict__ wr,
    float* __restrict__ logits, int* __restrict__ sel8, float* __restrict__ w8)
{
  int tid = threadIdx.x;
  int t = blockIdx.x * 4 + (tid >> 6);
  int lane = tid & 63;
  const float* xt = x + (long)t * H_DIM;
  float acc[E_NUM];
#pragma unroll
  for (int e = 0; e < E_NUM; ++e) acc[e] = 0.f;
  for (int h = lane * 4; h < H_DIM; h += 64 * 4) {
    float4 xv = *(const float4*)(xt + h);
#pragma unroll
    for (int e = 0; e < E_NUM; ++e) {
      float4 wv = *(const float4*)(wr + e * H_DIM + h);
      acc[e] += xv.x * wv.x + xv.y * wv.y + xv.z * wv.z + xv.w * wv.w;
    }
  }
#pragma unroll
  for (int e = 0; e < E_NUM; ++e) {
    float v = acc[e];
#pragma unroll
    for (int s = 32; s > 0; s >>= 1) v += __shfl_xor(v, s);
    acc[e] = v;
  }
  if (lane == 0) {
    float l[E_NUM]; float m = -3.4e38f;
#pragma unroll
    for (int e = 0; e < E_NUM; ++e) {
      l[e] = acc[e];
      logits[(long)t * E_NUM + e] = l[e];
      if (l[e] > m) m = l[e];
    }
    bool used[E_NUM];
#pragma unroll
    for (int e = 0; e < E_NUM; ++e) used[e] = false;
    int sel[K_TOP]; float ex[K_TOP]; float s = 0.f;
    for (int k = 0; k < K_TOP; ++k) {
      int best = 0; float bv = -3.4e38f;
      for (int e = 0; e < E_NUM; ++e)
        if (!used[e] && l[e] > bv) { bv = l[e]; best = e; }   // strict > = low-index tiebreak like lax.top_k
      used[best] = true; sel[k] = best;
      float ee = expf(bv - m); ex[k] = ee; s += ee;
    }
    float inv = 1.f / s;
    for (int k = 0; k < K_TOP; ++k) {
      sel8[t * K_TOP + k] = sel[k];
      w8[t * K_TOP + k] = ex[k] * inv;   // == topk-softmax renorm
    }
  }
}

// ---------------- per-block LDS histogram -> 16 global atomics per block ----------------
__global__ __launch_bounds__(256) void k_hist(const int* __restrict__ sel8, int* __restrict__ cnt) {
  __shared__ int lh[E_NUM];
  int tid = threadIdx.x;
  if (tid < E_NUM) lh[tid] = 0;
  __syncthreads();
  int t = blockIdx.x * 256 + tid;
#pragma unroll
  for (int k = 0; k < K_TOP; ++k) atomicAdd(&lh[sel8[t * K_TOP + k]], 1);
  __syncthreads();
  if (tid < E_NUM) atomicAdd(&cnt[tid], lh[tid]);
}

// ---------------- scan + tile table (256-row tiles; trivial sizes; single thread) ----------------
__global__ void k_scan(int* ib) {
  if (threadIdx.x != 0 || blockIdx.x != 0) return;
  int o = 0, nt = 0;
  for (int e = 0; e < E_NUM; ++e) {
    ib[IB_OFFS + e] = o;
    ib[IB_CURS + e] = o;
    int c = ib[IB_CNT + e];
    for (int p = 0; p < c; p += 256) { ib[IB_TE + nt] = e; ib[IB_TP + nt] = o + p; ++nt; }
    o += c;
  }
  ib[IB_OFFS + E_NUM] = o;
  ib[IB_NT] = nt;
}

// ---------------- pair-list build: block reserves per-expert ranges (16 atomics/block) ----------------
__global__ __launch_bounds__(256) void k_build(
    const int* __restrict__ sel8, const float* __restrict__ w8,
    int* ib, int* __restrict__ ptok, float* __restrict__ pw,
    int* __restrict__ pidx)
{
  __shared__ int lh[E_NUM], lbase[E_NUM];
  int tid = threadIdx.x;
  if (tid < E_NUM) lh[tid] = 0;
  __syncthreads();
  int t = blockIdx.x * 256 + tid;
  int e8[K_TOP], r8[K_TOP];
#pragma unroll
  for (int k = 0; k < K_TOP; ++k) {
    int e = sel8[t * K_TOP + k];
    e8[k] = e;
    r8[k] = atomicAdd(&lh[e], 1);        // LDS atomic: local rank within block
  }
  __syncthreads();
  if (tid < E_NUM) lbase[tid] = atomicAdd(&ib[IB_CURS + tid], lh[tid]);
  __syncthreads();
#pragma unroll
  for (int k = 0; k < K_TOP; ++k) {
    int pos = lbase[e8[k]] + r8[k];
    ptok[pos] = t; pw[pos] = w8[t * K_TOP + k]; pidx[t * K_TOP + k] = pos;
  }
}

// ---------------- fp32 -> bf16 casts ----------------
__global__ void k_cast_plain(const float* __restrict__ src, unsigned short* __restrict__ dst, long n4) {
  long i = (long)blockIdx.x * 256 + threadIdx.x;
  if (i >= n4) return;
  long i4 = i * 4;
  float4 v = *(const float4*)(src + i4);
  short4v o; o.x = (short)f2bf(v.x); o.y = (short)f2bf(v.y); o.z = (short)f2bf(v.z); o.w = (short)f2bf(v.w);
  *(short4v*)(dst + i4) = o;
}

// row-padded: src [E][RS][C] -> dst [E][RD][C], rows >= RS zeroed (C % 4 == 0)
__global__ void k_cast_padrow(const float* __restrict__ src, unsigned short* __restrict__ dst,
                              int RS, int RD, int C, long n4) {
  long i = (long)blockIdx.x * 256 + threadIdx.x;
  if (i >= n4) return;
  long i4 = i * 4;
  long rowc = (long)RD * C;
  long e = i4 / rowc;
  long rem = i4 - e * rowc;
  int r = (int)(rem / C);
  int c = (int)(rem - (long)r * C);
  short4v o;
  if (r < RS) {
    float4 v = *(const float4*)(src + ((long)e * RS + r) * C + c);
    o.x = (short)f2bf(v.x); o.y = (short)f2bf(v.y); o.z = (short)f2bf(v.z); o.w = (short)f2bf(v.w);
  } else { o.x = 0; o.y = 0; o.z = 0; o.w = 0; }
  *(short4v*)(dst + i4) = o;
}

// col-padded, vectorized: src [R][CS] -> dst [R][CD], cols >= CS zeroed. CD % 8 == 0.
__global__ void k_cast_padcol(const float* __restrict__ src, unsigned short* __restrict__ dst,
                              int CS, int CD, long n8) {
  long i = (long)blockIdx.x * 256 + threadIdx.x;
  if (i >= n8) return;
  int cpr = CD >> 3;                 // chunks per row
  long row = i / cpr;
  int c0 = (int)(i - row * cpr) << 3;
  const float* srow = src + row * CS;
  short8 o;
#pragma unroll
  for (int j = 0; j < 8; ++j) {
    int c = c0 + j;
    o[j] = (c < CS) ? (short)f2bf(srow[c]) : (short)0;
  }
  *(short8*)(dst + row * CD + c0) = o;
}

// ---------------- deep-pipelined GEMM mainloop: 256x128 tile, BK=64, 8 waves (4Mx2N) ----------------
// NT layout: A [M,K] row-major, B [N,K] row-major. 16x16x32 bf16 MFMA, 64x64 per wave.
// LDS: double-buffered As[2][256x64] (64KB) + Bs[2][128x64] (32KB) = 96KB, 1 block/CU.
// Schedule per K-tile: counted vmcnt(6) (next tile's 6 gload_lds stay in flight across the
// barrier), 4 quadrant phases {ds_read subtile -> setprio(1) -> 8 MFMA -> setprio(0)},
// mid-barrier frees the buffer, STAGE(t+2) issued before the last MFMA quadrant.
// LDS XOR-swizzle (T2): 16B chunk index ^= (row&7), applied on BOTH the global source
// (pre-swizzled per-lane address; gload_lds dest stays linear) and the ds_read address.
template <bool GATHER>
__device__ __forceinline__ void gemm256_loop(
    const unsigned short* __restrict__ A, int lda,
    const unsigned short* __restrict__ B, int ldb,
    int arow0, int segend, const int* __restrict__ ptok,
    int n0, int K,
    char* As, char* Bs,
    f32x4 (&acc)[4][4])
{
  const int tid = threadIdx.x;
  const int srow = tid >> 3;                        // 0..63 staging row within an 8KB issue
  const int sc = (((tid & 7) ^ (srow & 7)) << 4);   // swizzled source chunk (bytes)
  const char* ap[4]; const char* bp[2];
#pragma unroll
  for (int i = 0; i < 4; ++i) {
    int rr = srow + i * 64;
    int arow;
    if (GATHER) {
      int p = arow0 + rr;
      if (p > segend - 1) p = segend - 1;           // clamp; masked at store
      arow = ptok[p];
    } else {
      arow = arow0 + rr;                            // pair buffers have 256 rows of slack
    }
    ap[i] = (const char*)A + (long)arow * (lda * 2) + sc;
  }
#pragma unroll
  for (int i = 0; i < 2; ++i)
    bp[i] = (const char*)B + (long)(n0 + srow + i * 64) * (ldb * 2) + sc;

  char* asd = As + tid * 16;   // linear LDS dest (gload_lds requirement)
  char* bsd = Bs + tid * 16;
  const int NT = K >> 6;

  asm volatile("s_waitcnt vmcnt(0)" ::: "memory");  // ptok gathers drained: vmcnt now counts stages only
  // prologue: stage K-tiles 0,1 (12 loads in flight per wave)
#pragma unroll
  for (int t = 0; t < 2; ++t) {
#pragma unroll
    for (int i = 0; i < 4; ++i) { gload16(ap[i], asd + t * 32768 + i * 8192); ap[i] += 128; }
#pragma unroll
    for (int i = 0; i < 2; ++i) { gload16(bp[i], bsd + t * 16384 + i * 8192); bp[i] += 128; }
  }

  const int lane = tid & 63, wave = tid >> 6;
  const int wm = (wave >> 1) << 6, wn = (wave & 1) << 6;
  const int m16 = lane & 15, kg = lane >> 4;
  const int sw0 = ((kg << 4) ^ ((m16 & 7) << 4));   // swizzled k-chunk byte offset (kk=0)
  const int aoff = (wm + m16) << 7;                 // row byte offset in A tile
  const int boff = (wn + m16) << 7;

  short8 af[4][2], bfv[4][2];

  for (int t = 0; t < NT; ++t) {
    const int buf = t & 1;
    if (t + 1 < NT) { asm volatile("s_waitcnt vmcnt(6)" ::: "memory"); }   // tile t landed; t+1 in flight
    else            { asm volatile("s_waitcnt vmcnt(0)" ::: "memory"); }
    __builtin_amdgcn_s_barrier();
    asm volatile("" ::: "memory");
    const char* Ab = As + buf * 32768;
    const char* Bb = Bs + buf * 16384;

    // ph1: read A(0,1), B(0,1); MFMA quadrant (0,0)
#pragma unroll
    for (int i = 0; i < 2; ++i) {
      af[i][0] = *(const short8*)(Ab + aoff + i * 2048 + sw0);
      af[i][1] = *(const short8*)(Ab + aoff + i * 2048 + (sw0 ^ 64));
    }
#pragma unroll
    for (int j = 0; j < 2; ++j) {
      bfv[j][0] = *(const short8*)(Bb + boff + j * 2048 + sw0);
      bfv[j][1] = *(const short8*)(Bb + boff + j * 2048 + (sw0 ^ 64));
    }
    __builtin_amdgcn_s_setprio(1);
#pragma unroll
    for (int i = 0; i < 2; ++i)
#pragma unroll
      for (int j = 0; j < 2; ++j)
#pragma unroll
        for (int kk = 0; kk < 2; ++kk)
          acc[i][j] = __builtin_amdgcn_mfma_f32_16x16x32_bf16(af[i][kk], bfv[j][kk], acc[i][j], 0, 0, 0);
    __builtin_amdgcn_s_setprio(0);

    // ph2: read B(2,3); MFMA quadrant (0,1)
#pragma unroll
    for (int j = 2; j < 4; ++j) {
      bfv[j][0] = *(const short8*)(Bb + boff + j * 2048 + sw0);
      bfv[j][1] = *(const short8*)(Bb + boff + j * 2048 + (sw0 ^ 64));
    }
    __builtin_amdgcn_s_setprio(1);
#pragma unroll
    for (int i = 0; i < 2; ++i)
#pragma unroll
      for (int j = 2; j < 4; ++j)
#pragma unroll
        for (int kk = 0; kk < 2; ++kk)
          acc[i][j] = __builtin_amdgcn_mfma_f32_16x16x32_bf16(af[i][kk], bfv[j][kk], acc[i][j], 0, 0, 0);
    __builtin_amdgcn_s_setprio(0);

    // ph3: read A(2,3); MFMA quadrant (1,0)
#pragma unroll
    for (int i = 2; i < 4; ++i) {
      af[i][0] = *(const short8*)(Ab + aoff + i * 2048 + sw0);
      af[i][1] = *(const short8*)(Ab + aoff + i * 2048 + (sw0 ^ 64));
    }
    __builtin_amdgcn_s_setprio(1);
#pragma unroll
    for (int i = 2; i < 4; ++i)
#pragma unroll
      for (int j = 0; j < 2; ++j)
#pragma unroll
        for (int kk = 0; kk < 2; ++kk)
          acc[i][j] = __builtin_amdgcn_mfma_f32_16x16x32_bf16(af[i][kk], bfv[j][kk], acc[i][j], 0, 0, 0);
    __builtin_amdgcn_s_setprio(0);

    // reads of this buffer done -> free it, prefetch tile t+2 into it
    asm volatile("s_waitcnt lgkmcnt(0)" ::: "memory");
    __builtin_amdgcn_s_barrier();
    asm volatile("" ::: "memory");
    if (t + 2 < NT) {
#pragma unroll
      for (int i = 0; i < 4; ++i) { gload16(ap[i], asd + buf * 32768 + i * 8192); ap[i] += 128; }
#pragma unroll
      for (int i = 0; i < 2; ++i) { gload16(bp[i], bsd + buf * 16384 + i * 8192); bp[i] += 128; }
    }
    __builtin_amdgcn_sched_barrier(0);   // keep ph4 MFMAs below the stage issues

    // ph4: MFMA quadrant (1,1) overlaps the in-flight stage
    __builtin_amdgcn_s_setprio(1);
#pragma unroll
    for (int i = 2; i < 4; ++i)
#pragma unroll
      for (int j = 2; j < 4; ++j)
#pragma unroll
        for (int kk = 0; kk < 2; ++kk)
          acc[i][j] = __builtin_amdgcn_mfma_f32_16x16x32_bf16(af[i][kk], bfv[j][kk], acc[i][j], 0, 0, 0);
    __builtin_amdgcn_s_setprio(0);
  }
}

// ---------------- dense NT GEMM (full M), blockIdx.y selects (B,out) pair ----------------
template <int OUTF32>
__global__ __launch_bounds__(512, 2) void k_gemm_dense(
    const unsigned short* __restrict__ A,
    const unsigned short* __restrict__ B0, const unsigned short* __restrict__ B1,
    void* out0, void* out1, int K, int ldc, int ny)
{
  extern __shared__ __attribute__((aligned(16))) char smem[];
  const unsigned short* B = blockIdx.y ? B1 : B0;
  void* outp = blockIdx.y ? out1 : out0;
  int bx, n0;
  swz_decode(blockIdx.x, gridDim.x, ny, bx, n0);
  int m0 = bx * 256;
  f32x4 acc[4][4];
  f32x4 z = {0.f, 0.f, 0.f, 0.f};
#pragma unroll
  for (int i = 0; i < 4; ++i)
#pragma unroll
    for (int j = 0; j < 4; ++j) acc[i][j] = z;
  gemm256_loop<false>(A, K, B, K, m0, 0, nullptr, n0, K, smem, smem + 65536, acc);

  int tid = threadIdx.x, lane = tid & 63, wave = tid >> 6;
  int wm = (wave >> 1) * 64, wn = (wave & 1) * 64, m16 = lane & 15, kg = lane >> 4;
#pragma unroll
  for (int i = 0; i < 4; ++i)
#pragma unroll
    for (int r = 0; r < 4; ++r) {
      int row = m0 + wm + i * 16 + kg * 4 + r;
#pragma unroll
      for (int j = 0; j < 4; ++j) {
        int col = n0 + wn + j * 16 + m16;
        if (OUTF32) ((float*)outp)[(long)row * ldc + col] = acc[i][j][r];
        else ((unsigned short*)outp)[(long)row * ldc + col] = f2bf(acc[i][j][r]);
      }
    }
}

// ---------------- grouped (per-expert pair-segment) NT GEMM ----------------
// MODE 0: T = gather(xb) @ Aexp^T            -> outT bf16 [pair, ldo]
// MODE 1: HW = silu(T @ Bg^T + base_g[tok])  -> HW bf16 [pair, I]
// MODE 2: HW = pw * HW * (T @ Bu^T + base_u[tok])   (in-place)
// MODE 3: T = A @ Bexp^T                     -> outT bf16 [pair, ldo]  (plain store)
template <int MODE>
__global__ __launch_bounds__(512, 2) void k_gemm_pairs(
    const int* __restrict__ ib,
    const int* __restrict__ ptok, const float* __restrict__ pw,
    const unsigned short* __restrict__ A, int lda,
    const unsigned short* __restrict__ Bbase, long bstrideE, int ldb,
    unsigned short* __restrict__ outT, int ldo,
    const unsigned short* __restrict__ baseGU,
    unsigned short* __restrict__ HW,
    int K, int ny)
{
  int nt = ib[IB_NT];
  int bx, n0;
  swz_decode(blockIdx.x, gridDim.x, ny, bx, n0);
  if (bx >= nt) return;
  int e = ib[IB_TE + bx];
  int p0 = ib[IB_TP + bx];
  int segend = ib[IB_OFFS + e + 1];
  const unsigned short* B = Bbase + (long)e * bstrideE;

  extern __shared__ __attribute__((aligned(16))) char smem[];
  f32x4 acc[4][4];
  f32x4 zz = {0.f, 0.f, 0.f, 0.f};
#pragma unroll
  for (int i = 0; i < 4; ++i)
#pragma unroll
    for (int j = 0; j < 4; ++j) acc[i][j] = zz;

  gemm256_loop<(MODE == 0)>(A, lda, B, ldb, p0, segend, ptok, n0, K, smem, smem + 65536, acc);

  int tid = threadIdx.x, lane = tid & 63, wave = tid >> 6;
  int wm = (wave >> 1) * 64, wn = (wave & 1) * 64, m16 = lane & 15, kg = lane >> 4;
#pragma unroll
  for (int i = 0; i < 4; ++i)
#pragma unroll
    for (int r = 0; r < 4; ++r) {
      int prow = p0 + wm + i * 16 + kg * 4 + r;
      if (prow >= segend) continue;
      if (MODE == 0 || MODE == 3) {
        unsigned short* orow = outT + (long)prow * ldo + n0 + wn + m16;
#pragma unroll
        for (int j = 0; j < 4; ++j) orow[j * 16] = f2bf(acc[i][j][r]);
      } else if (MODE == 1) {
        int tok = ptok[prow];
        const unsigned short* brow = baseGU + (long)tok * I_DIM + n0 + wn + m16;
        unsigned short* hrow = HW + (long)prow * I_DIM + n0 + wn + m16;
#pragma unroll
        for (int j = 0; j < 4; ++j) {
          float g = acc[i][j][r] + bf2f(brow[j * 16]);
          float sg = g / (1.f + expf(-g));          // silu
          hrow[j * 16] = f2bf(sg);
        }
      } else if (MODE == 2) {
        int tok = ptok[prow];
        float w = pw[prow];
        const unsigned short* brow = baseGU + (long)tok * I_DIM + n0 + wn + m16;
        unsigned short* hrow = HW + (long)prow * I_DIM + n0 + wn + m16;
#pragma unroll
        for (int j = 0; j < 4; ++j) {
          float u = acc[i][j][r] + bf2f(brow[j * 16]);
          float hv = w * bf2f(hrow[j * 16]) * u;    // combine weight folded in
          hrow[j * 16] = f2bf(hv);
        }
      }
    }
}

// ---------------- hbar[t] = sum_k HW[pair(t,k)] ----------------
__global__ void k_combine(const unsigned short* __restrict__ HW, const int* __restrict__ pidx,
                          unsigned short* __restrict__ hbar)
{
  long idx = (long)blockIdx.x * 256 + threadIdx.x;
  if (idx >= (long)T_TOK * (I_DIM / 8)) return;
  int t = (int)(idx >> 7);
  int c = ((int)idx & 127) << 3;
  const int* pi = pidx + t * 8;
  float s[8];
#pragma unroll
  for (int j = 0; j < 8; ++j) s[j] = 0.f;
  for (int k = 0; k < 8; ++k) {
    short8 v = *(const short8*)(HW + (long)pi[k] * I_DIM + c);
#pragma unroll
    for (int j = 0; j < 8; ++j) s[j] += bf2f((unsigned short)v[j]);
  }
  short8 o;
#pragma unroll
  for (int j = 0; j < 8; ++j) o[j] = (short)f2bf(s[j]);
  *(short8*)(hbar + (long)t * I_DIM + c) = o;
}

// ---------------- out[t, colOff + c] += sum_k P[pair(t,k), c]  (no atomics) ----------------
__global__ void k_fincomb(const unsigned short* __restrict__ P, const int* __restrict__ pidx,
                          float* __restrict__ out, int colOff)
{
  long idx = (long)blockIdx.x * 256 + threadIdx.x;
  if (idx >= (long)T_TOK * (I_DIM / 8)) return;   // 1024 cols per pass, 8 per thread
  int t = (int)(idx >> 7);
  int c = ((int)idx & 127) << 3;
  const int* pi = pidx + t * 8;
  float s[8];
#pragma unroll
  for (int j = 0; j < 8; ++j) s[j] = 0.f;
  for (int k = 0; k < 8; ++k) {
    short8 v = *(const short8*)(P + (long)pi[k] * I_DIM + c);
#pragma unroll
    for (int j = 0; j < 8; ++j) s[j] += bf2f((unsigned short)v[j]);
  }
  float* o = out + (long)t * H_DIM + colOff + c;
  float4 a0 = *(float4*)(o);
  float4 a1 = *(float4*)(o + 4);
  a0.x += s[0]; a0.y += s[1]; a0.z += s[2]; a0.w += s[3];
  a1.x += s[4]; a1.y += s[5]; a1.z += s[6]; a1.w += s[7];
  *(float4*)(o) = a0;
  *(float4*)(o + 4) = a1;
}

// ---------------- launch ----------------
#define SMEM_BYTES 98304

extern "C" void kernel_launch(void* const* d_in, const int* in_sizes, int n_in,
                              void* d_out, int out_size, void* d_ws, size_t ws_size,
                              hipStream_t stream) {
  const float* x  = (const float*)d_in[0];
  const float* wr = (const float*)d_in[1];
  const float* Wg = (const float*)d_in[2];
  const float* Wu = (const float*)d_in[3];
  const float* Wd = (const float*)d_in[4];
  const float* Ag = (const float*)d_in[5];
  const float* Bg = (const float*)d_in[6];
  const float* Au = (const float*)d_in[7];
  const float* Bu = (const float*)d_in[8];
  const float* Ad = (const float*)d_in[9];
  const float* Bd = (const float*)d_in[10];
  float* out = (float*)d_out;
  float* logits = out + (long)T_TOK * H_DIM;

  // ---- workspace layout (~350 MB, regions reused sequentially) ----
  char* p = (char*)d_ws;
  auto alloc = [&](size_t bytes) { char* r = p; p += (bytes + 255) & ~(size_t)255; return r; };
  unsigned short* xb    = (unsigned short*)alloc((size_t)T_TOK * H_DIM * 2);          // 33.6 MB
  unsigned short* WBA   = (unsigned short*)alloc((size_t)E_NUM * RP * H_DIM * 2);     // 41.9 MB (Wg+Wu / Ag / Au / Ad / Bd)
  unsigned short* WBB   = (unsigned short*)alloc((size_t)E_NUM * I_DIM * RP * 2);     // 21.0 MB (Bg / Bu / Wd)
  unsigned short* baseg = (unsigned short*)alloc((size_t)T_TOK * I_DIM * 2);          // 16.8 MB (later: hbar)
  unsigned short* baseu = (unsigned short*)alloc((size_t)T_TOK * I_DIM * 2);          // 16.8 MB
  unsigned short* Tbuf  = (unsigned short*)alloc((size_t)NPAIR_PAD * RP * 2);         // 84.2 MB
  unsigned short* HWb   = (unsigned short*)alloc((size_t)NPAIR_PAD * I_DIM * 2);      // 134.7 MB (later: P halves)
  int*   ibuf  = (int*)alloc(IB_TOTAL * 4);
  int*   sel8  = (int*)alloc((size_t)T_TOK * K_TOP * 4);
  float* w8    = (float*)alloc((size_t)T_TOK * K_TOP * 4);
  int*   ptok  = (int*)alloc((size_t)NPAIR * 4);
  float* pwv   = (float*)alloc((size_t)NPAIR * 4);
  int*   pidx  = (int*)alloc((size_t)T_TOK * K_TOP * 4);
  unsigned short* hbar = baseg;   // overlay: baseg dead before hbar written
  (void)ws_size; (void)n_in; (void)in_sizes; (void)out_size;

  hipMemsetAsync(ibuf, 0, 16 * 4, stream);  // expert counts

  // x -> bf16; routing (fp32-exact, contention-free)
  k_cast_plain<<<16384, 256, 0, stream>>>(x, xb, (long)T_TOK * H_DIM / 4);
  k_logits<<<T_TOK / 4, 256, 0, stream>>>(x, wr, logits, sel8, w8);
  k_hist<<<T_TOK / 256, 256, 0, stream>>>(sel8, ibuf + IB_CNT);
  k_scan<<<1, 1, 0, stream>>>(ibuf);
  k_build<<<T_TOK / 256, 256, 0, stream>>>(sel8, w8, ibuf, ptok, pwv, pidx);

  // base_g / base_u = xb @ {Wg,Wu}^T   (Wg,Wu staged in WBA)
  unsigned short* Wgb = WBA;
  unsigned short* Wub = WBA + (size_t)I_DIM * H_DIM;
  k_cast_plain<<<2048, 256, 0, stream>>>(Wg, Wgb, (long)I_DIM * H_DIM / 4);
  k_cast_plain<<<2048, 256, 0, stream>>>(Wu, Wub, (long)I_DIM * H_DIM / 4);
  k_gemm_dense<0><<<dim3((T_TOK / 256) * (I_DIM / 128), 2), 512, SMEM_BYTES, stream>>>(
      xb, Wgb, Wub, baseg, baseu, H_DIM, I_DIM, I_DIM / 128);

  // g path: T = gather(xb) @ Ag_e^T ; HW = silu(T @ Bg_e^T + base_g)
  k_cast_padrow<<<20480, 256, 0, stream>>>(Ag, WBA, R_RANK, RP, H_DIM, (long)E_NUM * RP * H_DIM / 4);
  k_gemm_pairs<0><<<MAX_TILES * (RP / 128), 512, SMEM_BYTES, stream>>>(
      ibuf, ptok, pwv, xb, H_DIM, WBA, (long)RP * H_DIM, H_DIM,
      Tbuf, RP, nullptr, nullptr, H_DIM, RP / 128);
  k_cast_padcol<<<5120, 256, 0, stream>>>(Bg, WBB, R_RANK, RP, (long)E_NUM * I_DIM * RP / 8);
  k_gemm_pairs<1><<<MAX_TILES * (I_DIM / 128), 512, SMEM_BYTES, stream>>>(
      ibuf, ptok, pwv, Tbuf, RP, WBB, (long)I_DIM * RP, RP,
      nullptr, I_DIM, baseg, HWb, RP, I_DIM / 128);

  // u path (reuses Tbuf): T = gather(xb) @ Au_e^T ; HW = pw * HW * (T @ Bu_e^T + base_u)
  k_cast_padrow<<<20480, 256, 0, stream>>>(Au, WBA, R_RANK, RP, H_DIM, (long)E_NUM * RP * H_DIM / 4);
  k_gemm_pairs<0><<<MAX_TILES * (RP / 128), 512, SMEM_BYTES, stream>>>(
      ibuf, ptok, pwv, xb, H_DIM, WBA, (long)RP * H_DIM, H_DIM,
      Tbuf, RP, nullptr, nullptr, H_DIM, RP / 128);
  k_cast_padcol<<<5120, 256, 0, stream>>>(Bu, WBB, R_RANK, RP, (long)E_NUM * I_DIM * RP / 8);
  k_gemm_pairs<2><<<MAX_TILES * (I_DIM / 128), 512, SMEM_BYTES, stream>>>(
      ibuf, ptok, pwv, Tbuf, RP, WBB, (long)I_DIM * RP, RP,
      nullptr, I_DIM, baseu, HWb, RP, I_DIM / 128);

  // hbar = per-token sum of weighted h   (overlaid on baseg, which is now dead)
  k_combine<<<(T_TOK * (I_DIM / 8)) / 256, 256, 0, stream>>>(HWb, pidx, hbar);

  // down LoRA stage 1: T = HW @ Ad_e^T
  k_cast_padrow<<<10240, 256, 0, stream>>>(Ad, WBA, R_RANK, RP, I_DIM, (long)E_NUM * RP * I_DIM / 4);
  k_gemm_pairs<3><<<MAX_TILES * (RP / 128), 512, SMEM_BYTES, stream>>>(
      ibuf, ptok, pwv, HWb, I_DIM, WBA, (long)RP * I_DIM, I_DIM,
      Tbuf, RP, nullptr, nullptr, I_DIM, RP / 128);

  // out = hbar @ Wd^T  (fp32 store, full coverage; Wd staged in WBB)
  k_cast_plain<<<2048, 256, 0, stream>>>(Wd, WBB, (long)H_DIM * I_DIM / 4);
  k_gemm_dense<1><<<dim3((T_TOK / 256) * (H_DIM / 128), 1), 512, SMEM_BYTES, stream>>>(
      hbar, WBB, WBB, out, out, I_DIM, H_DIM, H_DIM / 128);

  // out += T @ Bd_e^T — two half-N passes staged in HWb (dead now),
  // each followed by a coalesced per-token combine-add.
  k_cast_padcol<<<10240, 256, 0, stream>>>(Bd, WBA, R_RANK, RP, (long)E_NUM * H_DIM * RP / 8);
  for (int half = 0; half < 2; ++half) {
    k_gemm_pairs<3><<<MAX_TILES * (I_DIM / 128), 512, SMEM_BYTES, stream>>>(
        ibuf, ptok, pwv, Tbuf, RP, WBA + (long)half * I_DIM * RP, (long)H_DIM * RP, RP,
        HWb, I_DIM, nullptr, nullptr, RP, I_DIM / 128);
    k_fincomb<<<(T_TOK * (I_DIM / 8)) / 256, 256, 0, stream>>>(
        HWb, pidx, out, half * I_DIM);
  }
}

// Round 4
// 2007.323 us; speedup vs baseline: 1.0132x; 1.0132x over previous
//
#include <hip/hip_runtime.h>
#include <stdint.h>
#include <math.h>

// Problem constants (fixed by the reference)
#define T_TOK 8192      // B*S tokens
#define H_DIM 2048
#define I_DIM 1024
#define E_NUM 16
#define K_TOP 8
#define R_RANK 602
#define RP 640          // rank padded to 5*128 (zero-padded weights)
#define NPAIR 65536     // T_TOK * K_TOP (exact)
#define NPAIR_PAD (NPAIR + 128)
#define MAX_TILES 528   // sum ceil(Ne/128) <= 65536/128 + 16

typedef __attribute__((ext_vector_type(8))) short short8;
typedef __attribute__((ext_vector_type(4))) short short4v;
typedef __attribute__((ext_vector_type(4))) float f32x4;

__device__ __forceinline__ float bf2f(unsigned short s) {
  union { unsigned int i; float f; } u; u.i = ((unsigned int)s) << 16; return u.f;
}
__device__ __forceinline__ unsigned short f2bf(float f) {
  union { float f; unsigned int i; } u; u.f = f;
  unsigned int r = u.i + 0x7FFFu + ((u.i >> 16) & 1u);   // RNE, inputs finite
  return (unsigned short)(r >> 16);
}

typedef __attribute__((address_space(1))) const unsigned int glob_u32;
typedef __attribute__((address_space(3))) unsigned int lds_u32;

__device__ __forceinline__ void gload16(const void* g, void* l) {
  // async global->LDS, 16B per lane; LDS dest must be wave-uniform base + lane*16
  __builtin_amdgcn_global_load_lds((glob_u32*)g, (lds_u32*)l, 16, 0, 0);
}

// int-metadata buffer layout (in units of int)
#define IB_CNT  0
#define IB_OFFS 16
#define IB_CURS 33
#define IB_NT   49
#define IB_TE   50
#define IB_TP   (50 + MAX_TILES)
#define IB_TOTAL (50 + 2 * MAX_TILES)

// XCD-chunked bijective swizzle: consecutive work-ids on the SAME XCD,
// N-fastest decode so all n-tiles of one A-tile run back-to-back on one L2.
// Valid bijection when W % 8 == 0 (all our grids are multiples of 8).
__device__ __forceinline__ void swz_decode(int L, int W, int ny, int& bx, int& n0) {
  int w = (L & 7) * (W >> 3) + (L >> 3);
  bx = w / ny;
  n0 = (w - bx * ny) * 128;
}

// ---------------- logits + top-8 (no atomics; 4 waves/block, wave per token) ----------------
__global__ __launch_bounds__(256) void k_logits(
    const float* __restrict__ x, const float* __restrict__ wr,
    float* __restrict__ logits, int* __restrict__ sel8, float* __restrict__ w8)
{
  int tid = threadIdx.x;
  int t = blockIdx.x * 4 + (tid >> 6);
  int lane = tid & 63;
  const float* xt = x + (long)t * H_DIM;
  float acc[E_NUM];
#pragma unroll
  for (int e = 0; e < E_NUM; ++e) acc[e] = 0.f;
  for (int h = lane * 4; h < H_DIM; h += 64 * 4) {
    float4 xv = *(const float4*)(xt + h);
#pragma unroll
    for (int e = 0; e < E_NUM; ++e) {
      float4 wv = *(const float4*)(wr + e * H_DIM + h);
      acc[e] += xv.x * wv.x + xv.y * wv.y + xv.z * wv.z + xv.w * wv.w;
    }
  }
#pragma unroll
  for (int e = 0; e < E_NUM; ++e) {
    float v = acc[e];
#pragma unroll
    for (int s = 32; s > 0; s >>= 1) v += __shfl_xor(v, s);
    acc[e] = v;
  }
  if (lane == 0) {
    float l[E_NUM]; float m = -3.4e38f;
#pragma unroll
    for (int e = 0; e < E_NUM; ++e) {
      l[e] = acc[e];
      logits[(long)t * E_NUM + e] = l[e];
      if (l[e] > m) m = l[e];
    }
    bool used[E_NUM];
#pragma unroll
    for (int e = 0; e < E_NUM; ++e) used[e] = false;
    int sel[K_TOP]; float ex[K_TOP]; float s = 0.f;
    for (int k = 0; k < K_TOP; ++k) {
      int best = 0; float bv = -3.4e38f;
      for (int e = 0; e < E_NUM; ++e)
        if (!used[e] && l[e] > bv) { bv = l[e]; best = e; }   // strict > = low-index tiebreak like lax.top_k
      used[best] = true; sel[k] = best;
      float ee = expf(bv - m); ex[k] = ee; s += ee;
    }
    float inv = 1.f / s;
    for (int k = 0; k < K_TOP; ++k) {
      sel8[t * K_TOP + k] = sel[k];
      w8[t * K_TOP + k] = ex[k] * inv;   // == topk-softmax renorm
    }
  }
}

// ---------------- per-block LDS histogram -> 16 global atomics per block ----------------
__global__ __launch_bounds__(256) void k_hist(const int* __restrict__ sel8, int* __restrict__ cnt) {
  __shared__ int lh[E_NUM];
  int tid = threadIdx.x;
  if (tid < E_NUM) lh[tid] = 0;
  __syncthreads();
  int t = blockIdx.x * 256 + tid;
#pragma unroll
  for (int k = 0; k < K_TOP; ++k) atomicAdd(&lh[sel8[t * K_TOP + k]], 1);
  __syncthreads();
  if (tid < E_NUM) atomicAdd(&cnt[tid], lh[tid]);
}

// ---------------- scan + tile table (trivial sizes; single thread) ----------------
__global__ void k_scan(int* ib) {
  if (threadIdx.x != 0 || blockIdx.x != 0) return;
  int o = 0, nt = 0;
  for (int e = 0; e < E_NUM; ++e) {
    ib[IB_OFFS + e] = o;
    ib[IB_CURS + e] = o;
    int c = ib[IB_CNT + e];
    for (int p = 0; p < c; p += 128) { ib[IB_TE + nt] = e; ib[IB_TP + nt] = o + p; ++nt; }
    o += c;
  }
  ib[IB_OFFS + E_NUM] = o;
  ib[IB_NT] = nt;
}

// ---------------- pair-list build: block reserves per-expert ranges (16 atomics/block) ----------------
__global__ __launch_bounds__(256) void k_build(
    const int* __restrict__ sel8, const float* __restrict__ w8,
    int* ib, int* __restrict__ ptok, float* __restrict__ pw,
    int* __restrict__ pidx)
{
  __shared__ int lh[E_NUM], lbase[E_NUM];
  int tid = threadIdx.x;
  if (tid < E_NUM) lh[tid] = 0;
  __syncthreads();
  int t = blockIdx.x * 256 + tid;
  int e8[K_TOP], r8[K_TOP];
#pragma unroll
  for (int k = 0; k < K_TOP; ++k) {
    int e = sel8[t * K_TOP + k];
    e8[k] = e;
    r8[k] = atomicAdd(&lh[e], 1);        // LDS atomic: local rank within block
  }
  __syncthreads();
  if (tid < E_NUM) lbase[tid] = atomicAdd(&ib[IB_CURS + tid], lh[tid]);
  __syncthreads();
#pragma unroll
  for (int k = 0; k < K_TOP; ++k) {
    int pos = lbase[e8[k]] + r8[k];
    ptok[pos] = t; pw[pos] = w8[t * K_TOP + k]; pidx[t * K_TOP + k] = pos;
  }
}

// ---------------- fp32 -> bf16 casts ----------------
__global__ void k_cast_plain(const float* __restrict__ src, unsigned short* __restrict__ dst, long n4) {
  long i = (long)blockIdx.x * 256 + threadIdx.x;
  if (i >= n4) return;
  long i4 = i * 4;
  float4 v = *(const float4*)(src + i4);
  short4v o; o.x = (short)f2bf(v.x); o.y = (short)f2bf(v.y); o.z = (short)f2bf(v.z); o.w = (short)f2bf(v.w);
  *(short4v*)(dst + i4) = o;
}

// row-padded: src [E][RS][C] -> dst [E][RD][C], rows >= RS zeroed (C % 4 == 0)
__global__ void k_cast_padrow(const float* __restrict__ src, unsigned short* __restrict__ dst,
                              int RS, int RD, int C, long n4) {
  long i = (long)blockIdx.x * 256 + threadIdx.x;
  if (i >= n4) return;
  long i4 = i * 4;
  long rowc = (long)RD * C;
  long e = i4 / rowc;
  long rem = i4 - e * rowc;
  int r = (int)(rem / C);
  int c = (int)(rem - (long)r * C);
  short4v o;
  if (r < RS) {
    float4 v = *(const float4*)(src + ((long)e * RS + r) * C + c);
    o.x = (short)f2bf(v.x); o.y = (short)f2bf(v.y); o.z = (short)f2bf(v.z); o.w = (short)f2bf(v.w);
  } else { o.x = 0; o.y = 0; o.z = 0; o.w = 0; }
  *(short4v*)(dst + i4) = o;
}

// col-padded, vectorized: src [R][CS] -> dst [R][CD], cols >= CS zeroed. CD % 8 == 0.
__global__ void k_cast_padcol(const float* __restrict__ src, unsigned short* __restrict__ dst,
                              int CS, int CD, long n8) {
  long i = (long)blockIdx.x * 256 + threadIdx.x;
  if (i >= n8) return;
  int cpr = CD >> 3;                 // chunks per row
  long row = i / cpr;
  int c0 = (int)(i - row * cpr) << 3;
  const float* srow = src + row * CS;
  short8 o;
#pragma unroll
  for (int j = 0; j < 8; ++j) {
    int c = c0 + j;
    o[j] = (c < CS) ? (short)f2bf(srow[c]) : (short)0;
  }
  *(short8*)(dst + row * CD + c0) = o;
}

// ---------------- shared GEMM mainloop: 128x128 tile, BK=64, 16x16x32 bf16 MFMA ----------------
// NT layout everywhere: A [M,K] row-major, B [N,K] row-major.
// Staging: async global_load_lds width=16 (m97-style). PROVEN structure (round-1, 2000us).
template <bool GATHER>
__device__ __forceinline__ void gemm_tile_loop(
    const unsigned short* __restrict__ A, int lda,
    const unsigned short* __restrict__ B, int ldb,
    int arow0, int segend, const int* __restrict__ ptok,
    int n0, int K,
    unsigned short* As, unsigned short* Bs,
    f32x4 (&acc)[4][4])
{
  const int tid = threadIdx.x;
  const int srow = tid >> 3;            // staging row (+ i*32)
  const int scolb = (tid & 7) * 16;     // staging byte col within 128B row
  const char* ap[4]; const char* bp[4];
#pragma unroll
  for (int i = 0; i < 4; ++i) {
    int rr = srow + i * 32;
    int arow;
    if (GATHER) {
      int p = arow0 + rr;
      if (p > segend - 1) p = segend - 1;  // clamp; masked at store
      arow = ptok[p];
    } else {
      arow = arow0 + rr;                   // pair buffers have 128 rows of slack
    }
    ap[i] = (const char*)A + (long)arow * lda * 2 + scolb;
    bp[i] = (const char*)B + (long)(n0 + rr) * ldb * 2 + scolb;
  }
  const int lane = tid & 63;
  const int wave = tid >> 6;
  const int wm = (wave >> 1) * 64, wn = (wave & 1) * 64;
  const int m16 = lane & 15, kg = lane >> 4;

  for (int kt = 0; kt < K; kt += 64) {
#pragma unroll
    for (int i = 0; i < 4; ++i) {
      gload16(ap[i], As + (i * 256 + tid) * 8);
      gload16(bp[i], Bs + (i * 256 + tid) * 8);
      ap[i] += 128; bp[i] += 128;
    }
    __syncthreads();   // drains vmcnt (async LDS DMA) before LDS reads
#pragma unroll
    for (int kk = 0; kk < 2; ++kk) {
      short8 af[4], bfr[4];
#pragma unroll
      for (int i = 0; i < 4; ++i)
        af[i] = *(const short8*)(As + (wm + i * 16 + m16) * 64 + kk * 32 + kg * 8);
#pragma unroll
      for (int j = 0; j < 4; ++j)
        bfr[j] = *(const short8*)(Bs + (wn + j * 16 + m16) * 64 + kk * 32 + kg * 8);
#pragma unroll
      for (int i = 0; i < 4; ++i)
#pragma unroll
        for (int j = 0; j < 4; ++j)
          acc[i][j] = __builtin_amdgcn_mfma_f32_16x16x32_bf16(af[i], bfr[j], acc[i][j], 0, 0, 0);
    }
    __syncthreads();   // protect LDS before next stage
  }
}

// ---------------- shared-A dual-B mainloop: A staged ONCE, two B tiles, dual acc ----------------
// MFMA:gload = 32:12 (vs 16:8) -> +33% staging intensity on the shared-A GEMMs.
template <bool GATHER>
__device__ __forceinline__ void gemm_tile_loop_ab2(
    const unsigned short* __restrict__ A, int lda,
    const unsigned short* __restrict__ B0, const unsigned short* __restrict__ B1, int ldb,
    int arow0, int segend, const int* __restrict__ ptok,
    int n0, int K,
    unsigned short* As, unsigned short* Bs0, unsigned short* Bs1,
    f32x4 (&acc0)[4][4], f32x4 (&acc1)[4][4])
{
  const int tid = threadIdx.x;
  const int srow = tid >> 3;
  const int scolb = (tid & 7) * 16;
  const char* ap[4]; const char* b0p[4]; const char* b1p[4];
#pragma unroll
  for (int i = 0; i < 4; ++i) {
    int rr = srow + i * 32;
    int arow;
    if (GATHER) {
      int p = arow0 + rr;
      if (p > segend - 1) p = segend - 1;
      arow = ptok[p];
    } else {
      arow = arow0 + rr;
    }
    ap[i]  = (const char*)A  + (long)arow * lda * 2 + scolb;
    b0p[i] = (const char*)B0 + (long)(n0 + rr) * ldb * 2 + scolb;
    b1p[i] = (const char*)B1 + (long)(n0 + rr) * ldb * 2 + scolb;
  }
  const int lane = tid & 63;
  const int wave = tid >> 6;
  const int wm = (wave >> 1) * 64, wn = (wave & 1) * 64;
  const int m16 = lane & 15, kg = lane >> 4;

  for (int kt = 0; kt < K; kt += 64) {
#pragma unroll
    for (int i = 0; i < 4; ++i) {
      gload16(ap[i],  As  + (i * 256 + tid) * 8);
      gload16(b0p[i], Bs0 + (i * 256 + tid) * 8);
      gload16(b1p[i], Bs1 + (i * 256 + tid) * 8);
      ap[i] += 128; b0p[i] += 128; b1p[i] += 128;
    }
    __syncthreads();
#pragma unroll
    for (int kk = 0; kk < 2; ++kk) {
      short8 af[4], bf0[4], bf1[4];
#pragma unroll
      for (int i = 0; i < 4; ++i)
        af[i] = *(const short8*)(As + (wm + i * 16 + m16) * 64 + kk * 32 + kg * 8);
#pragma unroll
      for (int j = 0; j < 4; ++j) {
        bf0[j] = *(const short8*)(Bs0 + (wn + j * 16 + m16) * 64 + kk * 32 + kg * 8);
        bf1[j] = *(const short8*)(Bs1 + (wn + j * 16 + m16) * 64 + kk * 32 + kg * 8);
      }
#pragma unroll
      for (int i = 0; i < 4; ++i)
#pragma unroll
        for (int j = 0; j < 4; ++j) {
          acc0[i][j] = __builtin_amdgcn_mfma_f32_16x16x32_bf16(af[i], bf0[j], acc0[i][j], 0, 0, 0);
          acc1[i][j] = __builtin_amdgcn_mfma_f32_16x16x32_bf16(af[i], bf1[j], acc1[i][j], 0, 0, 0);
        }
    }
    __syncthreads();
  }
}

// ---------------- dual-A dual-B mainloop (no gather): (A0,B0)->acc0, (A1,B1)->acc1 ----------------
__device__ __forceinline__ void gemm_tile_loop_aabb(
    const unsigned short* __restrict__ A0, const unsigned short* __restrict__ A1, int lda,
    const unsigned short* __restrict__ B0, const unsigned short* __restrict__ B1, int ldb,
    int arow0, int n0, int K,
    unsigned short* As0, unsigned short* As1,
    unsigned short* Bs0, unsigned short* Bs1,
    f32x4 (&acc0)[4][4], f32x4 (&acc1)[4][4])
{
  const int tid = threadIdx.x;
  const int srow = tid >> 3;
  const int scolb = (tid & 7) * 16;
  const char* a0p[4]; const char* a1p[4]; const char* b0p[4]; const char* b1p[4];
#pragma unroll
  for (int i = 0; i < 4; ++i) {
    int rr = srow + i * 32;
    a0p[i] = (const char*)A0 + (long)(arow0 + rr) * lda * 2 + scolb;
    a1p[i] = (const char*)A1 + (long)(arow0 + rr) * lda * 2 + scolb;
    b0p[i] = (const char*)B0 + (long)(n0 + rr) * ldb * 2 + scolb;
    b1p[i] = (const char*)B1 + (long)(n0 + rr) * ldb * 2 + scolb;
  }
  const int lane = tid & 63;
  const int wave = tid >> 6;
  const int wm = (wave >> 1) * 64, wn = (wave & 1) * 64;
  const int m16 = lane & 15, kg = lane >> 4;

  for (int kt = 0; kt < K; kt += 64) {
#pragma unroll
    for (int i = 0; i < 4; ++i) {
      gload16(a0p[i], As0 + (i * 256 + tid) * 8);
      gload16(a1p[i], As1 + (i * 256 + tid) * 8);
      gload16(b0p[i], Bs0 + (i * 256 + tid) * 8);
      gload16(b1p[i], Bs1 + (i * 256 + tid) * 8);
      a0p[i] += 128; a1p[i] += 128; b0p[i] += 128; b1p[i] += 128;
    }
    __syncthreads();
#pragma unroll
    for (int kk = 0; kk < 2; ++kk) {
      {
        short8 af[4], bfr[4];
#pragma unroll
        for (int i = 0; i < 4; ++i)
          af[i] = *(const short8*)(As0 + (wm + i * 16 + m16) * 64 + kk * 32 + kg * 8);
#pragma unroll
        for (int j = 0; j < 4; ++j)
          bfr[j] = *(const short8*)(Bs0 + (wn + j * 16 + m16) * 64 + kk * 32 + kg * 8);
#pragma unroll
        for (int i = 0; i < 4; ++i)
#pragma unroll
          for (int j = 0; j < 4; ++j)
            acc0[i][j] = __builtin_amdgcn_mfma_f32_16x16x32_bf16(af[i], bfr[j], acc0[i][j], 0, 0, 0);
      }
      {
        short8 af[4], bfr[4];
#pragma unroll
        for (int i = 0; i < 4; ++i)
          af[i] = *(const short8*)(As1 + (wm + i * 16 + m16) * 64 + kk * 32 + kg * 8);
#pragma unroll
        for (int j = 0; j < 4; ++j)
          bfr[j] = *(const short8*)(Bs1 + (wn + j * 16 + m16) * 64 + kk * 32 + kg * 8);
#pragma unroll
        for (int i = 0; i < 4; ++i)
#pragma unroll
          for (int j = 0; j < 4; ++j)
            acc1[i][j] = __builtin_amdgcn_mfma_f32_16x16x32_bf16(af[i], bfr[j], acc1[i][j], 0, 0, 0);
      }
    }
    __syncthreads();
  }
}

// ---------------- dense NT GEMM (full M), blockIdx.y selects (B,out) pair ----------------
template <int OUTF32>
__global__ __launch_bounds__(256, 2) void k_gemm_dense(
    const unsigned short* __restrict__ A,
    const unsigned short* __restrict__ B0, const unsigned short* __restrict__ B1,
    void* out0, void* out1, int K, int ldc, int ny)
{
  __shared__ __attribute__((aligned(16))) unsigned short As[128 * 64];
  __shared__ __attribute__((aligned(16))) unsigned short Bs[128 * 64];
  const unsigned short* B = blockIdx.y ? B1 : B0;
  void* outp = blockIdx.y ? out1 : out0;
  int m0, n0;
  swz_decode(blockIdx.x, gridDim.x, ny, m0, n0);
  m0 *= 128;
  f32x4 acc[4][4];
  f32x4 z = {0.f, 0.f, 0.f, 0.f};
#pragma unroll
  for (int i = 0; i < 4; ++i)
#pragma unroll
    for (int j = 0; j < 4; ++j) acc[i][j] = z;
  gemm_tile_loop<false>(A, K, B, K, m0, 0, nullptr, n0, K, As, Bs, acc);

  int tid = threadIdx.x, lane = tid & 63, wave = tid >> 6;
  int wm = (wave >> 1) * 64, wn = (wave & 1) * 64, m16 = lane & 15, kg = lane >> 4;
#pragma unroll
  for (int i = 0; i < 4; ++i)
#pragma unroll
    for (int r = 0; r < 4; ++r) {
      int row = m0 + wm + i * 16 + kg * 4 + r;
#pragma unroll
      for (int j = 0; j < 4; ++j) {
        int col = n0 + wn + j * 16 + m16;
        if (OUTF32) ((float*)outp)[(long)row * ldc + col] = acc[i][j][r];
        else ((unsigned short*)outp)[(long)row * ldc + col] = f2bf(acc[i][j][r]);
      }
    }
}

// ---------------- fused dense: baseg/baseu in one pass (A staged once) ----------------
__global__ __launch_bounds__(256, 2) void k_gemm_dense2(
    const unsigned short* __restrict__ A,
    const unsigned short* __restrict__ B0, const unsigned short* __restrict__ B1,
    unsigned short* __restrict__ out0, unsigned short* __restrict__ out1,
    int K, int ldc, int ny)
{
  __shared__ __attribute__((aligned(16))) unsigned short As[128 * 64];
  __shared__ __attribute__((aligned(16))) unsigned short Bs0[128 * 64];
  __shared__ __attribute__((aligned(16))) unsigned short Bs1[128 * 64];
  int m0, n0;
  swz_decode(blockIdx.x, gridDim.x, ny, m0, n0);
  m0 *= 128;
  f32x4 acc0[4][4], acc1[4][4];
  f32x4 z = {0.f, 0.f, 0.f, 0.f};
#pragma unroll
  for (int i = 0; i < 4; ++i)
#pragma unroll
    for (int j = 0; j < 4; ++j) { acc0[i][j] = z; acc1[i][j] = z; }
  gemm_tile_loop_ab2<false>(A, K, B0, B1, K, m0, 0, nullptr, n0, K, As, Bs0, Bs1, acc0, acc1);

  int tid = threadIdx.x, lane = tid & 63, wave = tid >> 6;
  int wm = (wave >> 1) * 64, wn = (wave & 1) * 64, m16 = lane & 15, kg = lane >> 4;
#pragma unroll
  for (int i = 0; i < 4; ++i)
#pragma unroll
    for (int r = 0; r < 4; ++r) {
      int row = m0 + wm + i * 16 + kg * 4 + r;
#pragma unroll
      for (int j = 0; j < 4; ++j) {
        int col = n0 + wn + j * 16 + m16;
        out0[(long)row * ldc + col] = f2bf(acc0[i][j][r]);
        out1[(long)row * ldc + col] = f2bf(acc1[i][j][r]);
      }
    }
}

// ---------------- grouped (per-expert pair-segment) NT GEMM ----------------
// MODE 0: T = gather(xb) @ Aexp^T            -> outT bf16 [pair, ldo]
// MODE 1: HW = silu(T @ Bg^T + base_g[tok])  -> HW bf16 [pair, I]
// MODE 2: HW = pw * HW * (T @ Bu^T + base_u[tok])   (in-place)
// MODE 3: T = A @ Bexp^T                     -> outT bf16 [pair, ldo]  (plain store)
template <int MODE>
__global__ __launch_bounds__(256, 2) void k_gemm_pairs(
    const int* __restrict__ ib,
    const int* __restrict__ ptok, const float* __restrict__ pw,
    const unsigned short* __restrict__ A, int lda,
    const unsigned short* __restrict__ Bbase, long bstrideE, int ldb,
    unsigned short* __restrict__ outT, int ldo,
    const unsigned short* __restrict__ baseGU,
    unsigned short* __restrict__ HW,
    int K, int ny)
{
  int nt = ib[IB_NT];
  int bx, n0;
  swz_decode(blockIdx.x, gridDim.x, ny, bx, n0);
  if (bx >= nt) return;
  int e = ib[IB_TE + bx];
  int p0 = ib[IB_TP + bx];
  int segend = ib[IB_OFFS + e + 1];
  const unsigned short* B = Bbase + (long)e * bstrideE;

  __shared__ __attribute__((aligned(16))) unsigned short As[128 * 64];
  __shared__ __attribute__((aligned(16))) unsigned short Bs[128 * 64];
  f32x4 acc[4][4];
  f32x4 zz = {0.f, 0.f, 0.f, 0.f};
#pragma unroll
  for (int i = 0; i < 4; ++i)
#pragma unroll
    for (int j = 0; j < 4; ++j) acc[i][j] = zz;

  gemm_tile_loop<(MODE == 0)>(A, lda, B, ldb, p0, segend, ptok, n0, K, As, Bs, acc);

  int tid = threadIdx.x, lane = tid & 63, wave = tid >> 6;
  int wm = (wave >> 1) * 64, wn = (wave & 1) * 64, m16 = lane & 15, kg = lane >> 4;
#pragma unroll
  for (int i = 0; i < 4; ++i)
#pragma unroll
    for (int r = 0; r < 4; ++r) {
      int prow = p0 + wm + i * 16 + kg * 4 + r;
      if (prow >= segend) continue;
      if (MODE == 0 || MODE == 3) {
        unsigned short* orow = outT + (long)prow * ldo + n0 + wn + m16;
#pragma unroll
        for (int j = 0; j < 4; ++j) orow[j * 16] = f2bf(acc[i][j][r]);
      } else if (MODE == 1) {
        int tok = ptok[prow];
        const unsigned short* brow = baseGU + (long)tok * I_DIM + n0 + wn + m16;
        unsigned short* hrow = HW + (long)prow * I_DIM + n0 + wn + m16;
#pragma unroll
        for (int j = 0; j < 4; ++j) {
          float g = acc[i][j][r] + bf2f(brow[j * 16]);
          float sg = g / (1.f + expf(-g));          // silu
          hrow[j * 16] = f2bf(sg);
        }
      } else if (MODE == 2) {
        int tok = ptok[prow];
        float w = pw[prow];
        const unsigned short* brow = baseGU + (long)tok * I_DIM + n0 + wn + m16;
        unsigned short* hrow = HW + (long)prow * I_DIM + n0 + wn + m16;
#pragma unroll
        for (int j = 0; j < 4; ++j) {
          float u = acc[i][j][r] + bf2f(brow[j * 16]);
          float hv = w * bf2f(hrow[j * 16]) * u;    // combine weight folded in
          hrow[j * 16] = f2bf(hv);
        }
      }
    }
}

// ---------------- fused LoRA-A: Tg,Tu = gather(xb) @ {Ag,Au}^T in one pass ----------------
__global__ __launch_bounds__(256, 2) void k_gemm_pairs0_2(
    const int* __restrict__ ib, const int* __restrict__ ptok,
    const unsigned short* __restrict__ A, int lda,
    const unsigned short* __restrict__ B0base, const unsigned short* __restrict__ B1base,
    long bstrideE, int ldb,
    unsigned short* __restrict__ outT0, unsigned short* __restrict__ outT1, int ldo,
    int K, int ny)
{
  int nt = ib[IB_NT];
  int bx, n0;
  swz_decode(blockIdx.x, gridDim.x, ny, bx, n0);
  if (bx >= nt) return;
  int e = ib[IB_TE + bx];
  int p0 = ib[IB_TP + bx];
  int segend = ib[IB_OFFS + e + 1];
  const unsigned short* B0 = B0base + (long)e * bstrideE;
  const unsigned short* B1 = B1base + (long)e * bstrideE;

  __shared__ __attribute__((aligned(16))) unsigned short As[128 * 64];
  __shared__ __attribute__((aligned(16))) unsigned short Bs0[128 * 64];
  __shared__ __attribute__((aligned(16))) unsigned short Bs1[128 * 64];
  f32x4 acc0[4][4], acc1[4][4];
  f32x4 zz = {0.f, 0.f, 0.f, 0.f};
#pragma unroll
  for (int i = 0; i < 4; ++i)
#pragma unroll
    for (int j = 0; j < 4; ++j) { acc0[i][j] = zz; acc1[i][j] = zz; }

  gemm_tile_loop_ab2<true>(A, lda, B0, B1, ldb, p0, segend, ptok, n0, K, As, Bs0, Bs1, acc0, acc1);

  int tid = threadIdx.x, lane = tid & 63, wave = tid >> 6;
  int wm = (wave >> 1) * 64, wn = (wave & 1) * 64, m16 = lane & 15, kg = lane >> 4;
#pragma unroll
  for (int i = 0; i < 4; ++i)
#pragma unroll
    for (int r = 0; r < 4; ++r) {
      int prow = p0 + wm + i * 16 + kg * 4 + r;
      if (prow >= segend) continue;
      unsigned short* o0 = outT0 + (long)prow * ldo + n0 + wn + m16;
      unsigned short* o1 = outT1 + (long)prow * ldo + n0 + wn + m16;
#pragma unroll
      for (int j = 0; j < 4; ++j) {
        o0[j * 16] = f2bf(acc0[i][j][r]);
        o1[j * 16] = f2bf(acc1[i][j][r]);
      }
    }
}

// ---------------- fused LoRA-B + activation: HW = pw * silu(Tg@Bg^T + baseg) * (Tu@Bu^T + baseu) ----------------
__global__ __launch_bounds__(256, 2) void k_gemm_pairs12(
    const int* __restrict__ ib, const int* __restrict__ ptok, const float* __restrict__ pw,
    const unsigned short* __restrict__ A0, const unsigned short* __restrict__ A1, int lda,
    const unsigned short* __restrict__ B0base, const unsigned short* __restrict__ B1base,
    long bstrideE, int ldb,
    const unsigned short* __restrict__ baseg, const unsigned short* __restrict__ baseu,
    unsigned short* __restrict__ HW,
    int K, int ny)
{
  int nt = ib[IB_NT];
  int bx, n0;
  swz_decode(blockIdx.x, gridDim.x, ny, bx, n0);
  if (bx >= nt) return;
  int e = ib[IB_TE + bx];
  int p0 = ib[IB_TP + bx];
  int segend = ib[IB_OFFS + e + 1];
  const unsigned short* B0 = B0base + (long)e * bstrideE;
  const unsigned short* B1 = B1base + (long)e * bstrideE;

  __shared__ __attribute__((aligned(16))) unsigned short As0[128 * 64];
  __shared__ __attribute__((aligned(16))) unsigned short As1[128 * 64];
  __shared__ __attribute__((aligned(16))) unsigned short Bs0[128 * 64];
  __shared__ __attribute__((aligned(16))) unsigned short Bs1[128 * 64];
  f32x4 acc0[4][4], acc1[4][4];
  f32x4 zz = {0.f, 0.f, 0.f, 0.f};
#pragma unroll
  for (int i = 0; i < 4; ++i)
#pragma unroll
    for (int j = 0; j < 4; ++j) { acc0[i][j] = zz; acc1[i][j] = zz; }

  gemm_tile_loop_aabb(A0, A1, lda, B0, B1, ldb, p0, n0, K, As0, As1, Bs0, Bs1, acc0, acc1);

  int tid = threadIdx.x, lane = tid & 63, wave = tid >> 6;
  int wm = (wave >> 1) * 64, wn = (wave & 1) * 64, m16 = lane & 15, kg = lane >> 4;
#pragma unroll
  for (int i = 0; i < 4; ++i)
#pragma unroll
    for (int r = 0; r < 4; ++r) {
      int prow = p0 + wm + i * 16 + kg * 4 + r;
      if (prow >= segend) continue;
      int tok = ptok[prow];
      float w = pw[prow];
      const unsigned short* bg = baseg + (long)tok * I_DIM + n0 + wn + m16;
      const unsigned short* bu = baseu + (long)tok * I_DIM + n0 + wn + m16;
      unsigned short* hrow = HW + (long)prow * I_DIM + n0 + wn + m16;
#pragma unroll
      for (int j = 0; j < 4; ++j) {
        float g = acc0[i][j][r] + bf2f(bg[j * 16]);
        float u = acc1[i][j][r] + bf2f(bu[j * 16]);
        float sg = g / (1.f + expf(-g));            // silu
        hrow[j * 16] = f2bf(w * sg * u);            // combine weight folded in
      }
    }
}

// ---------------- hbar[t] = sum_k HW[pair(t,k)] ----------------
__global__ void k_combine(const unsigned short* __restrict__ HW, const int* __restrict__ pidx,
                          unsigned short* __restrict__ hbar)
{
  long idx = (long)blockIdx.x * 256 + threadIdx.x;
  if (idx >= (long)T_TOK * (I_DIM / 8)) return;
  int t = (int)(idx >> 7);
  int c = ((int)idx & 127) << 3;
  const int* pi = pidx + t * 8;
  float s[8];
#pragma unroll
  for (int j = 0; j < 8; ++j) s[j] = 0.f;
  for (int k = 0; k < 8; ++k) {
    short8 v = *(const short8*)(HW + (long)pi[k] * I_DIM + c);
#pragma unroll
    for (int j = 0; j < 8; ++j) s[j] += bf2f((unsigned short)v[j]);
  }
  short8 o;
#pragma unroll
  for (int j = 0; j < 8; ++j) o[j] = (short)f2bf(s[j]);
  *(short8*)(hbar + (long)t * I_DIM + c) = o;
}

// ---------------- out[t, colOff + c] += sum_k P[pair(t,k), c]  (no atomics) ----------------
__global__ void k_fincomb(const unsigned short* __restrict__ P, const int* __restrict__ pidx,
                          float* __restrict__ out, int colOff)
{
  long idx = (long)blockIdx.x * 256 + threadIdx.x;
  if (idx >= (long)T_TOK * (I_DIM / 8)) return;   // 1024 cols per pass, 8 per thread
  int t = (int)(idx >> 7);
  int c = ((int)idx & 127) << 3;
  const int* pi = pidx + t * 8;
  float s[8];
#pragma unroll
  for (int j = 0; j < 8; ++j) s[j] = 0.f;
  for (int k = 0; k < 8; ++k) {
    short8 v = *(const short8*)(P + (long)pi[k] * I_DIM + c);
#pragma unroll
    for (int j = 0; j < 8; ++j) s[j] += bf2f((unsigned short)v[j]);
  }
  float* o = out + (long)t * H_DIM + colOff + c;
  float4 a0 = *(float4*)(o);
  float4 a1 = *(float4*)(o + 4);
  a0.x += s[0]; a0.y += s[1]; a0.z += s[2]; a0.w += s[3];
  a1.x += s[4]; a1.y += s[5]; a1.z += s[6]; a1.w += s[7];
  *(float4*)(o) = a0;
  *(float4*)(o + 4) = a1;
}

// ---------------- launch ----------------
extern "C" void kernel_launch(void* const* d_in, const int* in_sizes, int n_in,
                              void* d_out, int out_size, void* d_ws, size_t ws_size,
                              hipStream_t stream) {
  const float* x  = (const float*)d_in[0];
  const float* wr = (const float*)d_in[1];
  const float* Wg = (const float*)d_in[2];
  const float* Wu = (const float*)d_in[3];
  const float* Wd = (const float*)d_in[4];
  const float* Ag = (const float*)d_in[5];
  const float* Bg = (const float*)d_in[6];
  const float* Au = (const float*)d_in[7];
  const float* Bu = (const float*)d_in[8];
  const float* Ad = (const float*)d_in[9];
  const float* Bd = (const float*)d_in[10];
  float* out = (float*)d_out;
  float* logits = out + (long)T_TOK * H_DIM;

  // ---- workspace layout, ws_size-adaptive ----
  // big (~503 MB): Ag|Au, Bg|Bu, Tg|Tu all live simultaneously -> operand-shared fused GEMMs
  // small (~352 MB): round-1 layout, sequential staging (proven path)
  char* base = (char*)d_ws;
  char* p = base;
  auto alloc = [&](size_t bytes) { char* r = p; p += (bytes + 255) & ~(size_t)255; return r; };
  unsigned short *xb, *WAg, *WAu, *WBg, *WBu, *baseg, *baseu, *Tg, *Tu, *HWb;
  int *ibuf, *sel8, *ptok, *pidx;
  float *w8, *pwv;
  auto layout = [&](bool bigf) {
    p = base;
    xb = (unsigned short*)alloc((size_t)T_TOK * H_DIM * 2);                 // 33.6 MB
    if (bigf) {
      WAg = (unsigned short*)alloc((size_t)E_NUM * RP * H_DIM * 2);         // 41.9 MB (later Ad, Bd)
      WAu = (unsigned short*)alloc((size_t)E_NUM * RP * H_DIM * 2);         // 41.9 MB
      WBg = (unsigned short*)alloc((size_t)E_NUM * I_DIM * RP * 2);         // 21.0 MB (later Wd)
      WBu = (unsigned short*)alloc((size_t)E_NUM * I_DIM * RP * 2);         // 21.0 MB
    } else {
      WAg = WAu = (unsigned short*)alloc((size_t)E_NUM * RP * H_DIM * 2);   // shared, staged sequentially
      WBg = WBu = (unsigned short*)alloc((size_t)E_NUM * I_DIM * RP * 2);
    }
    baseg = (unsigned short*)alloc((size_t)T_TOK * I_DIM * 2);              // 16.8 MB (later: hbar)
    baseu = (unsigned short*)alloc((size_t)T_TOK * I_DIM * 2);              // 16.8 MB
    if (bigf) {
      Tg = (unsigned short*)alloc((size_t)NPAIR_PAD * RP * 2);              // 84.0 MB
      Tu = (unsigned short*)alloc((size_t)NPAIR_PAD * RP * 2);              // 84.0 MB
    } else {
      Tg = Tu = (unsigned short*)alloc((size_t)NPAIR_PAD * RP * 2);
    }
    HWb = (unsigned short*)alloc((size_t)NPAIR_PAD * I_DIM * 2);            // 134.5 MB (also Wg/Wu scratch in big)
    ibuf = (int*)alloc(IB_TOTAL * 4);
    sel8 = (int*)alloc((size_t)T_TOK * K_TOP * 4);
    w8   = (float*)alloc((size_t)T_TOK * K_TOP * 4);
    ptok = (int*)alloc((size_t)NPAIR * 4);
    pwv  = (float*)alloc((size_t)NPAIR * 4);
    pidx = (int*)alloc((size_t)T_TOK * K_TOP * 4);
  };
  layout(true);
  const bool big = (size_t)(p - base) <= ws_size;
  if (!big) layout(false);
  unsigned short* hbar = baseg;   // overlay: baseg dead before hbar written
  (void)n_in; (void)in_sizes; (void)out_size;

  hipMemsetAsync(ibuf, 0, 16 * 4, stream);  // expert counts

  // x -> bf16; routing (fp32-exact, contention-free)
  k_cast_plain<<<16384, 256, 0, stream>>>(x, xb, (long)T_TOK * H_DIM / 4);
  k_logits<<<T_TOK / 4, 256, 0, stream>>>(x, wr, logits, sel8, w8);
  k_hist<<<T_TOK / 256, 256, 0, stream>>>(sel8, ibuf + IB_CNT);
  k_scan<<<1, 1, 0, stream>>>(ibuf);
  k_build<<<T_TOK / 256, 256, 0, stream>>>(sel8, w8, ibuf, ptok, pwv, pidx);

  // base_g / base_u = xb @ {Wg,Wu}^T.  Wg/Wu staged in HWb (big, dead until MODE12) or WAg (small).
  unsigned short* Wgb = big ? HWb : WAg;
  unsigned short* Wub = Wgb + (size_t)I_DIM * H_DIM;
  k_cast_plain<<<2048, 256, 0, stream>>>(Wg, Wgb, (long)I_DIM * H_DIM / 4);
  k_cast_plain<<<2048, 256, 0, stream>>>(Wu, Wub, (long)I_DIM * H_DIM / 4);
  if (big) {
    k_gemm_dense2<<<(T_TOK / 128) * (I_DIM / 128), 256, 0, stream>>>(
        xb, Wgb, Wub, baseg, baseu, H_DIM, I_DIM, I_DIM / 128);
  } else {
    k_gemm_dense<0><<<dim3((T_TOK / 128) * (I_DIM / 128), 2), 256, 0, stream>>>(
        xb, Wgb, Wub, baseg, baseu, H_DIM, I_DIM, I_DIM / 128);
  }

  if (big) {
    // fused g+u LoRA-A: Tg,Tu = gather(xb) @ {Ag,Au}^T  (A staged once)
    k_cast_padrow<<<20480, 256, 0, stream>>>(Ag, WAg, R_RANK, RP, H_DIM, (long)E_NUM * RP * H_DIM / 4);
    k_cast_padrow<<<20480, 256, 0, stream>>>(Au, WAu, R_RANK, RP, H_DIM, (long)E_NUM * RP * H_DIM / 4);
    k_gemm_pairs0_2<<<MAX_TILES * (RP / 128), 256, 0, stream>>>(
        ibuf, ptok, xb, H_DIM, WAg, WAu, (long)RP * H_DIM, H_DIM,
        Tg, Tu, RP, H_DIM, RP / 128);
    // fused LoRA-B + act: HW = pw * silu(Tg@Bg^T + baseg) * (Tu@Bu^T + baseu)  (single HW write)
    k_cast_padcol<<<5120, 256, 0, stream>>>(Bg, WBg, R_RANK, RP, (long)E_NUM * I_DIM * RP / 8);
    k_cast_padcol<<<5120, 256, 0, stream>>>(Bu, WBu, R_RANK, RP, (long)E_NUM * I_DIM * RP / 8);
    k_gemm_pairs12<<<MAX_TILES * (I_DIM / 128), 256, 0, stream>>>(
        ibuf, ptok, pwv, Tg, Tu, RP, WBg, WBu, (long)I_DIM * RP, RP,
        baseg, baseu, HWb, RP, I_DIM / 128);
  } else {
    // g path: T = gather(xb) @ Ag_e^T ; HW = silu(T @ Bg_e^T + base_g)
    k_cast_padrow<<<20480, 256, 0, stream>>>(Ag, WAg, R_RANK, RP, H_DIM, (long)E_NUM * RP * H_DIM / 4);
    k_gemm_pairs<0><<<MAX_TILES * (RP / 128), 256, 0, stream>>>(
        ibuf, ptok, pwv, xb, H_DIM, WAg, (long)RP * H_DIM, H_DIM,
        Tg, RP, nullptr, nullptr, H_DIM, RP / 128);
    k_cast_padcol<<<5120, 256, 0, stream>>>(Bg, WBg, R_RANK, RP, (long)E_NUM * I_DIM * RP / 8);
    k_gemm_pairs<1><<<MAX_TILES * (I_DIM / 128), 256, 0, stream>>>(
        ibuf, ptok, pwv, Tg, RP, WBg, (long)I_DIM * RP, RP,
        nullptr, I_DIM, baseg, HWb, RP, I_DIM / 128);
    // u path (reuses T buffer)
    k_cast_padrow<<<20480, 256, 0, stream>>>(Au, WAu, R_RANK, RP, H_DIM, (long)E_NUM * RP * H_DIM / 4);
    k_gemm_pairs<0><<<MAX_TILES * (RP / 128), 256, 0, stream>>>(
        ibuf, ptok, pwv, xb, H_DIM, WAu, (long)RP * H_DIM, H_DIM,
        Tu, RP, nullptr, nullptr, H_DIM, RP / 128);
    k_cast_padcol<<<5120, 256, 0, stream>>>(Bu, WBu, R_RANK, RP, (long)E_NUM * I_DIM * RP / 8);
    k_gemm_pairs<2><<<MAX_TILES * (I_DIM / 128), 256, 0, stream>>>(
        ibuf, ptok, pwv, Tu, RP, WBu, (long)I_DIM * RP, RP,
        nullptr, I_DIM, baseu, HWb, RP, I_DIM / 128);
  }

  // hbar = per-token sum of weighted h   (overlaid on baseg, which is now dead)
  k_combine<<<(T_TOK * (I_DIM / 8)) / 256, 256, 0, stream>>>(HWb, pidx, hbar);

  // down LoRA stage 1: T = HW @ Ad_e^T   (Ad staged in WAg, dead in both layouts)
  k_cast_padrow<<<10240, 256, 0, stream>>>(Ad, WAg, R_RANK, RP, I_DIM, (long)E_NUM * RP * I_DIM / 4);
  k_gemm_pairs<3><<<MAX_TILES * (RP / 128), 256, 0, stream>>>(
      ibuf, ptok, pwv, HWb, I_DIM, WAg, (long)RP * I_DIM, I_DIM,
      Tg, RP, nullptr, nullptr, I_DIM, RP / 128);

  // out = hbar @ Wd^T  (fp32 store, full coverage; Wd staged in WBg)
  k_cast_plain<<<2048, 256, 0, stream>>>(Wd, WBg, (long)H_DIM * I_DIM / 4);
  k_gemm_dense<1><<<dim3((T_TOK / 128) * (H_DIM / 128), 1), 256, 0, stream>>>(
      hbar, WBg, WBg, out, out, I_DIM, H_DIM, H_DIM / 128);

  // out += T @ Bd_e^T — two half-N passes staged in HWb (dead now),
  // each followed by a coalesced per-token combine-add.  (Bd staged in WAg.)
  k_cast_padcol<<<10240, 256, 0, stream>>>(Bd, WAg, R_RANK, RP, (long)E_NUM * H_DIM * RP / 8);
  for (int half = 0; half < 2; ++half) {
    k_gemm_pairs<3><<<MAX_TILES * (I_DIM / 128), 256, 0, stream>>>(
        ibuf, ptok, pwv, Tg, RP, WAg + (long)half * I_DIM * RP, (long)H_DIM * RP, RP,
        HWb, I_DIM, nullptr, nullptr, RP, I_DIM / 128);
    k_fincomb<<<(T_TOK * (I_DIM / 8)) / 256, 256, 0, stream>>>(
        HWb, pidx, out, half * I_DIM);
  }
}